// Round 9
// baseline (195.055 us; speedup 1.0000x reference)
//
#include <hip/hip_runtime.h>
#include <math.h>

#define B_N     16384
#define D_IN    784
#define D_HID   256
#define D_LAT   8
#define N_CTR   64
#define CH_N    64
#define N_CLS   10

#define DT_C    0.1f
#define EPS_C   1e-4f
#define PM_STEPS 4
#define TAU_C   0.9f
#define MGAIN   0.1f
#define EIG     0.06f
#define PLR_C   0.001f
#define T_STEPS 5

#define KP      832   // 784 padded to 13*64

typedef short bf16x8 __attribute__((ext_vector_type(8)));
typedef float f32x4v __attribute__((ext_vector_type(4)));

__device__ __forceinline__ void split_pair(float a, float b, unsigned& hi, unsigned& lo) {
    unsigned ua = __float_as_uint(a), ub = __float_as_uint(b);
    hi = (ua >> 16) | (ub & 0xffff0000u);
    float ra = a - __uint_as_float(ua & 0xffff0000u);
    float rb = b - __uint_as_float(ub & 0xffff0000u);
    lo = (__float_as_uint(ra) >> 16) | (__float_as_uint(rb) & 0xffff0000u);
}

__device__ __forceinline__ float fast_rcp(float x) { return __builtin_amdgcn_rcpf(x); }
__device__ __forceinline__ float fast_tanh(float a) {
    float e = __expf(2.0f * a);
    return 1.0f - 2.0f * fast_rcp(e + 1.0f);
}

// DPP xor-add within quads (full-rate VALU). 0xB1 = quad_perm xor1, 0x4E = quad_perm xor2.
#define DPP_XOR_ADD(v, CTRL) \
    ((v) + __int_as_float(__builtin_amdgcn_update_dpp(0, __float_as_int(v), (CTRL), 0xF, 0xF, true)))

// ---------------- w1t: W1[784][256] f32 -> WtH/WtL[256][832] bf16 (zero-padded) ----------------
__global__ __launch_bounds__(256) void w1t_kernel(
    const float* __restrict__ W1, ushort* __restrict__ WtH, ushort* __restrict__ WtL)
{
    __shared__ float t[32][36];
    const int kb = blockIdx.x;          // 0..25
    const int nb = blockIdx.y;          // 0..7
    const int tid = threadIdx.x;
    {
        const int r = tid >> 3, c4 = (tid & 7) * 4;
        const int k = kb * 32 + r;
        float4 v = {0.f, 0.f, 0.f, 0.f};
        if (k < D_IN) v = *(const float4*)(W1 + (size_t)k * 256 + nb * 32 + c4);
        t[r][c4 + 0] = v.x; t[r][c4 + 1] = v.y; t[r][c4 + 2] = v.z; t[r][c4 + 3] = v.w;
    }
    __syncthreads();
    const int n = tid >> 3, kq = (tid & 7) * 4;
    float a0 = t[kq + 0][n], a1 = t[kq + 1][n], a2 = t[kq + 2][n], a3 = t[kq + 3][n];
    unsigned h0, l0, h1w, l1w;
    split_pair(a0, a1, h0, l0);
    split_pair(a2, a3, h1w, l1w);
    const size_t o = (size_t)(nb * 32 + n) * KP + kb * 32 + kq;
    uint2 hv; hv.x = h0; hv.y = h1w;
    uint2 lv; lv.x = l0; lv.y = l1w;
    *(uint2*)(WtH + o) = hv;
    *(uint2*)(WtL + o) = lv;
}

// ================= enc1 shared body (round-6 proven structure) =================
// If SPLITK: writes raw acc to P (P0/P1 by k-half); else: tanh(acc+b1) -> h1.
template <bool SPLITK>
__global__ __launch_bounds__(256, 3) void enc1_tpl(
    const float* __restrict__ x, const ushort* __restrict__ WtH,
    const ushort* __restrict__ WtL, const float* __restrict__ b1,
    float* __restrict__ out0, float* __restrict__ out1)
{
    __shared__ alignas(16) unsigned char AhiS[16384];
    __shared__ alignas(16) unsigned char AloS[16384];
    __shared__ alignas(16) unsigned char BhiS[8192];
    __shared__ alignas(16) unsigned char BloS[8192];

    const int tid = threadIdx.x;
    const int bx  = blockIdx.x;
    int tile, half, kt0, kt1;
    if (SPLITK) {
        const int wk = (bx & 7) * 128 + (bx >> 3);   // bijective over 1024
        half = wk & 1;
        tile = wk >> 1;                              // 0..511
        kt0 = half ? 7 : 0;
        kt1 = half ? 13 : 7;
    } else {
        tile = (bx & 7) * 64 + (bx >> 3);            // bijective over 512
        half = 0; kt0 = 0; kt1 = 13;
    }
    const int n0 = (tile & 3) * 64;
    const int m0 = (tile >> 2) * 128;

    // staging maps (validated r4/r6)
    const int m_s = tid >> 1, kh = tid & 1;          // A: row, 32-k half
    const int n_s = tid >> 2, kq = tid & 3;          // B: row, 16-k quarter
    const float*  xrow = x + (size_t)(m0 + m_s) * D_IN;
    const ushort* bhrow = WtH + (size_t)(n0 + n_s) * KP + kq * 16;
    const ushort* blrow = WtL + (size_t)(n0 + n_s) * KP + kq * 16;
    const unsigned offB0 = (unsigned)(n_s * 128) + (unsigned)(((2 * kq)     ^ (n_s & 7)) << 4);
    const unsigned offB1 = (unsigned)(n_s * 128) + (unsigned)(((2 * kq + 1) ^ (n_s & 7)) << 4);

    // compute maps (validated)
    const int lane = tid & 63;
    const int wid  = tid >> 6;
    const int wm   = wid >> 1, wn = wid & 1;
    const int fr   = lane & 15, g = lane >> 4;
    const unsigned swz = (unsigned)((fr & 7) << 4);
    const int kgb  = g * 16;

    f32x4v acc[4][2];
    #pragma unroll
    for (int mi = 0; mi < 4; ++mi)
        #pragma unroll
        for (int ni = 0; ni < 2; ++ni) acc[mi][ni] = (f32x4v){0.f, 0.f, 0.f, 0.f};

    for (int kt = kt0; kt < kt1; ++kt) {
        // ---- A: load f32, split, ds_write (regs die here) ----
        const int kbase = kt * 64 + kh * 32;
        float4 av[8];
        #pragma unroll
        for (int q = 0; q < 8; ++q) {
            const int kk = kbase + q * 4;
            float4 z4 = {0.f, 0.f, 0.f, 0.f};
            av[q] = (kk < D_IN) ? *(const float4*)(xrow + kk) : z4;
        }
        #pragma unroll
        for (int q16 = 0; q16 < 4; ++q16) {
            uint4 hw, lw;
            split_pair(av[2 * q16].x,     av[2 * q16].y,     hw.x, lw.x);
            split_pair(av[2 * q16].z,     av[2 * q16].w,     hw.y, lw.y);
            split_pair(av[2 * q16 + 1].x, av[2 * q16 + 1].y, hw.z, lw.z);
            split_pair(av[2 * q16 + 1].z, av[2 * q16 + 1].w, hw.w, lw.w);
            const unsigned off = (unsigned)(m_s * 128) +
                (unsigned)((((kh * 4 + q16) ^ (m_s & 7))) << 4);
            *(uint4*)(AhiS + off) = hw;
            *(uint4*)(AloS + off) = lw;
        }
        // ---- B: pure copy (bf16 prebuilt) ----
        {
            const int ko = kt * 64;
            uint4 h0 = *(const uint4*)(bhrow + ko);
            uint4 h1v = *(const uint4*)(bhrow + ko + 8);
            uint4 l0 = *(const uint4*)(blrow + ko);
            uint4 l1v = *(const uint4*)(blrow + ko + 8);
            *(uint4*)(BhiS + offB0) = h0;
            *(uint4*)(BhiS + offB1) = h1v;
            *(uint4*)(BloS + offB0) = l0;
            *(uint4*)(BloS + offB1) = l1v;
        }
        __syncthreads();

        // ---- compute: 48 MFMA / wave ----
        #pragma unroll
        for (int ks = 0; ks < 2; ++ks) {
            const unsigned kb = (unsigned)(ks * 64 + kgb);
            bf16x8 ahv[4], alv[4];
            #pragma unroll
            for (int mi = 0; mi < 4; ++mi) {
                const unsigned off = (unsigned)((wm * 64 + mi * 16 + fr) * 128) + (kb ^ swz);
                ahv[mi] = *(const bf16x8*)(AhiS + off);
                alv[mi] = *(const bf16x8*)(AloS + off);
            }
            #pragma unroll
            for (int ni = 0; ni < 2; ++ni) {
                const unsigned offb = (unsigned)((wn * 32 + ni * 16 + fr) * 128) + (kb ^ swz);
                bf16x8 bh = *(const bf16x8*)(BhiS + offb);
                bf16x8 bl = *(const bf16x8*)(BloS + offb);
                #pragma unroll
                for (int mi = 0; mi < 4; ++mi) {
                    acc[mi][ni] = __builtin_amdgcn_mfma_f32_16x16x32_bf16(ahv[mi], bh, acc[mi][ni], 0, 0, 0);
                    acc[mi][ni] = __builtin_amdgcn_mfma_f32_16x16x32_bf16(ahv[mi], bl, acc[mi][ni], 0, 0, 0);
                    acc[mi][ni] = __builtin_amdgcn_mfma_f32_16x16x32_bf16(alv[mi], bh, acc[mi][ni], 0, 0, 0);
                }
            }
        }
        __syncthreads();
    }

    // ---- epilogue ----
    float* P = (SPLITK && half) ? out1 : out0;
    #pragma unroll
    for (int ni = 0; ni < 2; ++ni) {
        const int col = n0 + wn * 32 + ni * 16 + fr;
        const float bias = SPLITK ? 0.f : b1[col];
        #pragma unroll
        for (int mi = 0; mi < 4; ++mi) {
            #pragma unroll
            for (int r = 0; r < 4; ++r) {
                const int row = m0 + wm * 64 + mi * 16 + g * 4 + r;
                if (SPLITK)
                    P[(size_t)row * 256 + col] = acc[mi][ni][r];
                else
                    P[(size_t)row * 256 + col] = tanhf(acc[mi][ni][r] + bias);
            }
        }
    }
}

// ---------------- enc2 (fallback): zT[b][d] = h1[b,:] @ W2[:,d] + b2[d] ----------------
__global__ __launch_bounds__(256) void enc2_kernel(
    const float* __restrict__ h1, const float* __restrict__ W2,
    const float* __restrict__ b2, float* __restrict__ zT)
{
    __shared__ alignas(16) float hs[32][260];
    __shared__ alignas(16) float w2t[8][260];
    const int tid = threadIdx.x;
    const int r0 = blockIdx.x * 32;
    for (int i = tid; i < D_HID * D_LAT; i += 256) {
        int k = i >> 3, d = i & 7;
        w2t[d][k] = W2[i];
    }
    #pragma unroll
    for (int i = 0; i < 8; ++i) {
        int idx = tid + i * 256;
        int rr = idx >> 6, c4 = idx & 63;
        float4 v = *(const float4*)(h1 + (size_t)(r0 + rr) * D_HID + c4 * 4);
        *(float4*)&hs[rr][c4 * 4] = v;
    }
    __syncthreads();
    const int r = tid >> 3, d = tid & 7;
    float acc = 0.f;
    #pragma unroll 8
    for (int k4 = 0; k4 < 64; ++k4) {
        float4 a = *(const float4*)&hs[r][k4 * 4];
        float4 w = *(const float4*)&w2t[d][k4 * 4];
        acc = fmaf(a.x, w.x, acc);
        acc = fmaf(a.y, w.y, acc);
        acc = fmaf(a.z, w.z, acc);
        acc = fmaf(a.w, w.w, acc);
    }
    zT[(size_t)(r0 + r) * 8 + d] = acc + b2[d];
}

// ---------------- enc2s (split): combine P0+P1+bias, tanh, then @W2 ----------------
__global__ __launch_bounds__(256) void enc2s_kernel(
    const float* __restrict__ P0, const float* __restrict__ P1,
    const float* __restrict__ b1, const float* __restrict__ W2,
    const float* __restrict__ b2, float* __restrict__ zT)
{
    __shared__ alignas(16) float hs[32][260];
    __shared__ alignas(16) float w2t[8][260];
    const int tid = threadIdx.x;
    const int r0 = blockIdx.x * 32;
    for (int i = tid; i < D_HID * D_LAT; i += 256) {
        int k = i >> 3, d = i & 7;
        w2t[d][k] = W2[i];
    }
    #pragma unroll
    for (int i = 0; i < 8; ++i) {
        int idx = tid + i * 256;
        int rr = idx >> 6, c4 = idx & 63;
        const size_t off = (size_t)(r0 + rr) * D_HID + c4 * 4;
        float4 v0 = *(const float4*)(P0 + off);
        float4 v1 = *(const float4*)(P1 + off);
        float4 bv = *(const float4*)(b1 + c4 * 4);
        hs[rr][c4 * 4 + 0] = tanhf(v0.x + v1.x + bv.x);
        hs[rr][c4 * 4 + 1] = tanhf(v0.y + v1.y + bv.y);
        hs[rr][c4 * 4 + 2] = tanhf(v0.z + v1.z + bv.z);
        hs[rr][c4 * 4 + 3] = tanhf(v0.w + v1.w + bv.w);
    }
    __syncthreads();
    const int r = tid >> 3, d = tid & 7;
    float acc = 0.f;
    #pragma unroll 8
    for (int k4 = 0; k4 < 64; ++k4) {
        float4 a = *(const float4*)&hs[r][k4 * 4];
        float4 w = *(const float4*)&w2t[d][k4 * 4];
        acc = fmaf(a.x, w.x, acc);
        acc = fmaf(a.y, w.y, acc);
        acc = fmaf(a.z, w.z, acc);
        acc = fmaf(a.w, w.w, acc);
    }
    zT[(size_t)(r0 + r) * 8 + d] = acc + b2[d];
}

// ---------------- stepA2: round-6 proven version (8 lanes per b, DPP reduce) ----------------
__global__ __launch_bounds__(256) void stepA2_kernel(
    float* __restrict__ zT, float* __restrict__ hT,
    const float* __restrict__ mu, const float* __restrict__ c,
    const float* __restrict__ Wp, const float* __restrict__ bp,
    const float* __restrict__ Wr, const float* __restrict__ br,
    float* __restrict__ part, float* __restrict__ out, int t)
{
    __shared__ alignas(16) float mu_s[64];
    __shared__ alignas(16) float c_s[512];
    __shared__ alignas(16) float wp_s[512];
    __shared__ alignas(16) float bp_s[64];
    __shared__ alignas(16) float wr_s[704];
    __shared__ alignas(16) float br_s[16];
    __shared__ alignas(16) float act_s[32 * 72];
    __shared__ alignas(16) float z_s[256];
    __shared__ alignas(16) float post_s[32];
    __shared__ alignas(16) float red2[4 * 64 * 10];
    const int tid = threadIdx.x;
    if (tid < 64) { mu_s[tid] = mu[tid]; bp_s[tid] = bp[tid]; }
    for (int i = tid; i < 512; i += 256) { c_s[i] = c[i]; wp_s[i] = Wp[i]; }
    const bool last = (t == T_STEPS - 1);
    if (last) {
        for (int i = tid; i < 640; i += 256) wr_s[(i / 10) * 11 + (i % 10)] = Wr[i];
        if (tid < N_CLS) br_s[tid] = br[tid];
    }
    __syncthreads();

    const int sub  = tid & 7;
    const int grp  = tid >> 3;
    const int b    = blockIdx.x * 32 + grp;
    const int lane = tid & 63;
    const int gbase = lane & ~7;

    float zown = zT[(size_t)b * 8 + sub];
    float z[8];
    #pragma unroll
    for (int d = 0; d < 8; ++d) z[d] = __shfl(zown, gbase + d, 64);

    #pragma unroll 1
    for (int it = 0; it < PM_STEPS; ++it) {
        float f[8];
        #pragma unroll
        for (int d = 0; d < 8; ++d) f[d] = 0.f;
        #pragma unroll
        for (int k = 0; k < 8; ++k) {
            const int n = sub + 8 * k;
            float dx[8];
            float r2 = EPS_C;
            #pragma unroll
            for (int d = 0; d < 8; ++d) {
                dx[d] = c_s[n * 8 + d] - z[d];
                r2 = fmaf(dx[d], dx[d], r2);
            }
            float wgt = mu_s[n] * fast_rcp(r2);
            #pragma unroll
            for (int d = 0; d < 8; ++d) f[d] = fmaf(wgt, dx[d], f[d]);
        }
        #pragma unroll
        for (int d = 0; d < 8; ++d) f[d] = DPP_XOR_ADD(f[d], 0xB1);
        #pragma unroll
        for (int d = 0; d < 8; ++d) f[d] = DPP_XOR_ADD(f[d], 0x4E);
        #pragma unroll
        for (int d = 0; d < 8; ++d) f[d] += __shfl_xor(f[d], 4, 64);
        #pragma unroll
        for (int d = 0; d < 8; ++d) z[d] = fmaf(DT_C, f[d], z[d]);
    }
    float zsel = z[0];
    #pragma unroll
    for (int d = 1; d < 8; ++d) if (sub == d) zsel = z[d];
    zT[(size_t)b * 8 + sub] = zsel;

    float hn[8];
    float s = 0.f;
    #pragma unroll
    for (int j = 0; j < 8; ++j) {
        const int ch = sub * 8 + j;
        float a = bp_s[ch];
        #pragma unroll
        for (int d = 0; d < 8; ++d) a = fmaf(z[d], wp_s[d * 64 + ch], a);
        hn[j] = fast_tanh(a);
    }
    if (t == 0) {
        #pragma unroll
        for (int j = 0; j < 8; ++j) { hn[j] = MGAIN * hn[j]; s += hn[j]; }
    } else {
        const float4* hp = (const float4*)(hT + (size_t)b * 64 + sub * 8);
        float4 h0 = hp[0], h1v = hp[1];
        hn[0] = TAU_C * h0.x + MGAIN * hn[0];
        hn[1] = TAU_C * h0.y + MGAIN * hn[1];
        hn[2] = TAU_C * h0.z + MGAIN * hn[2];
        hn[3] = TAU_C * h0.w + MGAIN * hn[3];
        hn[4] = TAU_C * h1v.x + MGAIN * hn[4];
        hn[5] = TAU_C * h1v.y + MGAIN * hn[5];
        hn[6] = TAU_C * h1v.z + MGAIN * hn[6];
        hn[7] = TAU_C * h1v.w + MGAIN * hn[7];
        #pragma unroll
        for (int j = 0; j < 8; ++j) s += hn[j];
    }
    s = DPP_XOR_ADD(s, 0xB1);
    s = DPP_XOR_ADD(s, 0x4E);
    s += __shfl_xor(s, 4, 64);
    const float mean = s * (1.f / 64.f);
    float spost = 0.f;
    #pragma unroll
    for (int j = 0; j < 8; ++j) {
        hn[j] = hn[j] + EIG * (hn[j] - mean);
        spost += hn[j];
    }
    {
        float4 a0 = {hn[0], hn[1], hn[2], hn[3]};
        float4 a1 = {hn[4], hn[5], hn[6], hn[7]};
        float4* hp = (float4*)(hT + (size_t)b * 64 + sub * 8);
        hp[0] = a0; hp[1] = a1;
    }
    spost = DPP_XOR_ADD(spost, 0xB1);
    spost = DPP_XOR_ADD(spost, 0x4E);
    spost += __shfl_xor(spost, 4, 64);

    if (!last) {
        z_s[tid] = zsel;
        if (sub == 0) post_s[grp] = spost * (1.f / 64.f);
        #pragma unroll
        for (int k = 0; k < 8; ++k) {
            const int n = sub + 8 * k;
            float r2 = 0.f;
            #pragma unroll
            for (int d = 0; d < 8; ++d) {
                float dd = c_s[n * 8 + d] - z[d];
                r2 = fmaf(dd, dd, r2);
            }
            act_s[grp * 72 + n] = __expf(-r2);
        }
        __syncthreads();
        const int q = tid >> 6, n2 = tid & 63;
        float r[10];
        #pragma unroll
        for (int j = 0; j < 10; ++j) r[j] = 0.f;
        #pragma unroll
        for (int i = 0; i < 8; ++i) {
            const int g2 = q * 8 + i;
            float a = act_s[g2 * 72 + n2];
            const float4* zp = (const float4*)&z_s[g2 * 8];
            float4 za = zp[0], zb = zp[1];
            r[0] += a;
            r[1] = fmaf(a, post_s[g2], r[1]);
            r[2] = fmaf(a, za.x, r[2]);
            r[3] = fmaf(a, za.y, r[3]);
            r[4] = fmaf(a, za.z, r[4]);
            r[5] = fmaf(a, za.w, r[5]);
            r[6] = fmaf(a, zb.x, r[6]);
            r[7] = fmaf(a, zb.y, r[7]);
            r[8] = fmaf(a, zb.z, r[8]);
            r[9] = fmaf(a, zb.w, r[9]);
        }
        #pragma unroll
        for (int j = 0; j < 10; ++j) red2[(q * 64 + n2) * 10 + j] = r[j];
        __syncthreads();
        if (q == 0) {
            #pragma unroll
            for (int j = 0; j < 10; ++j) {
                float sv = (red2[(n2) * 10 + j] + red2[(64 + n2) * 10 + j]) +
                           (red2[(128 + n2) * 10 + j] + red2[(192 + n2) * 10 + j]);
                part[((size_t)blockIdx.x * 64 + n2) * 10 + j] = sv;
            }
        }
    } else {
        float lg[N_CLS];
        #pragma unroll
        for (int cls = 0; cls < N_CLS; ++cls) lg[cls] = 0.f;
        #pragma unroll
        for (int j = 0; j < 8; ++j) {
            const int ch = sub * 8 + j;
            #pragma unroll
            for (int cls = 0; cls < N_CLS; ++cls)
                lg[cls] = fmaf(hn[j], wr_s[ch * 11 + cls], lg[cls]);
        }
        #pragma unroll
        for (int cls = 0; cls < N_CLS; ++cls) {
            lg[cls] = DPP_XOR_ADD(lg[cls], 0xB1);
            lg[cls] = DPP_XOR_ADD(lg[cls], 0x4E);
            lg[cls] += __shfl_xor(lg[cls], 4, 64);
        }
        if (sub == 0) {
            #pragma unroll
            for (int cls = 0; cls < N_CLS; ++cls)
                out[(size_t)b * 10 + cls] = lg[cls] + br_s[cls];
        }
        out[163840 + (size_t)b * 8 + sub] = zsel;
        {
            float4 a0 = {hn[0], hn[1], hn[2], hn[3]};
            float4 a1 = {hn[4], hn[5], hn[6], hn[7]};
            float4* op = (float4*)(out + 294912 + (size_t)b * 64 + sub * 8);
            op[0] = a0; op[1] = a1;
        }
    }
}

// ---------------- stepB2: reduce 512 partials -> mu', c' ----------------
__global__ __launch_bounds__(256) void stepB2_kernel(
    const float* __restrict__ part,
    const float* __restrict__ mu_in, const float* __restrict__ c_in,
    float* __restrict__ mu_out, float* __restrict__ c_out)
{
    const int n = blockIdx.x, tid = threadIdx.x;
    __shared__ float red[256][10];
    const float* p0 = part + ((size_t)tid * 64 + n) * 10;
    const float* p1 = part + ((size_t)(tid + 256) * 64 + n) * 10;
    #pragma unroll
    for (int j = 0; j < 10; ++j) red[tid][j] = p0[j] + p1[j];
    __syncthreads();
    for (int s = 128; s > 0; s >>= 1) {
        if (tid < s) {
            #pragma unroll
            for (int j = 0; j < 10; ++j) red[tid][j] += red[tid + s][j];
        }
        __syncthreads();
    }
    if (tid == 0) {
        const float S1 = red[0][0];
        const float S2 = red[0][1] * (1.f / B_N);
        mu_out[n] = mu_in[n] + PLR_C * S2;
        const float denom = S1 + EPS_C;
        #pragma unroll
        for (int d = 0; d < 8; ++d) {
            float s3 = red[0][2 + d];
            c_out[n * 8 + d] = c_in[n * 8 + d] + PLR_C * (s3 / denom - c_in[n * 8 + d] * (S1 / denom));
        }
    }
}

extern "C" void kernel_launch(void* const* d_in, const int* in_sizes, int n_in,
                              void* d_out, int out_size, void* d_ws, size_t ws_size,
                              hipStream_t stream) {
    (void)in_sizes; (void)n_in; (void)out_size;
    const float* x   = (const float*)d_in[0];
    const float* W1  = (const float*)d_in[1];
    const float* b1  = (const float*)d_in[2];
    const float* W2  = (const float*)d_in[3];
    const float* b2  = (const float*)d_in[4];
    const float* mu0 = (const float*)d_in[5];
    const float* c0  = (const float*)d_in[6];
    const float* Wp  = (const float*)d_in[7];
    const float* bp  = (const float*)d_in[8];
    const float* Wr  = (const float*)d_in[9];
    const float* br  = (const float*)d_in[10];
    float* out = (float*)d_out;
    float* ws  = (float*)d_ws;

    const bool split = (ws_size >= 34935296ull);   // K-split path needs ~33.3 MB

    float *zT, *mu_buf, *c_buf, *hT, *part;
    ushort *WtH, *WtL;

    if (split) {
        // P0 = ws[0..4.19M), P1 = ws[4.19M..8.39M); hT/part alias P0 after enc2s.
        float* P0 = ws;
        float* P1 = ws + 4194304;
        hT     = ws;                         // [B][64]   (aliases P0)
        part   = ws + 2113536;               // [512][64][10] (aliases P0)
        zT     = ws + 8388608;               // [B][8]
        mu_buf = ws + 8519680;               // 2 x 64
        c_buf  = ws + 8519808;               // 2 x 512
        WtH    = (ushort*)(ws + 8520832);    // [256][832] bf16
        WtL    = (ushort*)(ws + 8627328);

        w1t_kernel<<<dim3(26, 8), 256, 0, stream>>>(W1, WtH, WtL);
        enc1_tpl<true><<<1024, 256, 0, stream>>>(x, WtH, WtL, b1, P0, P1);
        enc2s_kernel<<<512, 256, 0, stream>>>(P0, P1, b1, W2, b2, zT);
    } else {
        // round-6 fallback layout
        float* h1 = ws;                      // [B,256]
        hT     = ws;
        part   = ws + 2113536;
        zT     = ws + 4194304;
        mu_buf = ws + 4325376;
        c_buf  = ws + 4325504;
        WtH    = (ushort*)(ws + 4326528);
        WtL    = (ushort*)(ws + 4433024);

        w1t_kernel<<<dim3(26, 8), 256, 0, stream>>>(W1, WtH, WtL);
        enc1_tpl<false><<<512, 256, 0, stream>>>(x, WtH, WtL, b1, h1, nullptr);
        enc2_kernel<<<512, 256, 0, stream>>>(h1, W2, b2, zT);
    }

    const float* mu_cur = mu0;
    const float* c_cur  = c0;
    for (int t = 0; t < T_STEPS; ++t) {
        stepA2_kernel<<<512, 256, 0, stream>>>(zT, hT, mu_cur, c_cur, Wp, bp, Wr, br,
                                               part, out, t);
        if (t < T_STEPS - 1) {
            float* mo = mu_buf + (t & 1) * 64;
            float* co = c_buf  + (t & 1) * 512;
            stepB2_kernel<<<64, 256, 0, stream>>>(part, mu_cur, c_cur, mo, co);
            mu_cur = mo;
            c_cur  = co;
        }
    }
}

// Round 10
// 115.278 us; speedup vs baseline: 1.6920x; 1.6920x over previous
//
#include <hip/hip_runtime.h>
#include <math.h>

#define B_N     16384
#define D_IN    784
#define D_HID   256
#define D_LAT   8
#define N_CTR   64
#define CH_N    64
#define N_CLS   10

#define DT_C    0.1f
#define EPS_C   1e-4f
#define PM_STEPS 4
#define TAU_C   0.9f
#define MGAIN   0.1f
#define EIG     0.06f
#define PLR_C   0.001f
#define T_STEPS 5

#define KP      832   // 784 padded to 13*64

typedef short bf16x8 __attribute__((ext_vector_type(8)));
typedef float f32x4v __attribute__((ext_vector_type(4)));

__device__ __forceinline__ void split_pair(float a, float b, unsigned& hi, unsigned& lo) {
    unsigned ua = __float_as_uint(a), ub = __float_as_uint(b);
    hi = (ua >> 16) | (ub & 0xffff0000u);
    float ra = a - __uint_as_float(ua & 0xffff0000u);
    float rb = b - __uint_as_float(ub & 0xffff0000u);
    lo = (__float_as_uint(ra) >> 16) | (__float_as_uint(rb) & 0xffff0000u);
}

__device__ __forceinline__ float fast_rcp(float x) { return __builtin_amdgcn_rcpf(x); }
__device__ __forceinline__ float fast_tanh(float a) {
    float e = __expf(2.0f * a);
    return 1.0f - 2.0f * fast_rcp(e + 1.0f);
}

// DPP xor-add within quads (full-rate VALU). 0xB1 = quad_perm xor1, 0x4E = quad_perm xor2.
#define DPP_XOR_ADD(v, CTRL) \
    ((v) + __int_as_float(__builtin_amdgcn_update_dpp(0, __float_as_int(v), (CTRL), 0xF, 0xF, true)))

// ---------------- w1t: W1[784][256] f32 -> WtH/WtL[256][832] bf16 (zero-padded) ----------------
__global__ __launch_bounds__(256) void w1t_kernel(
    const float* __restrict__ W1, ushort* __restrict__ WtH, ushort* __restrict__ WtL)
{
    __shared__ float t[32][36];
    const int kb = blockIdx.x;          // 0..25
    const int nb = blockIdx.y;          // 0..7
    const int tid = threadIdx.x;
    {
        const int r = tid >> 3, c4 = (tid & 7) * 4;
        const int k = kb * 32 + r;
        float4 v = {0.f, 0.f, 0.f, 0.f};
        if (k < D_IN) v = *(const float4*)(W1 + (size_t)k * 256 + nb * 32 + c4);
        t[r][c4 + 0] = v.x; t[r][c4 + 1] = v.y; t[r][c4 + 2] = v.z; t[r][c4 + 3] = v.w;
    }
    __syncthreads();
    const int n = tid >> 3, kq = (tid & 7) * 4;
    float a0 = t[kq + 0][n], a1 = t[kq + 1][n], a2 = t[kq + 2][n], a3 = t[kq + 3][n];
    unsigned h0, l0, h1w, l1w;
    split_pair(a0, a1, h0, l0);
    split_pair(a2, a3, h1w, l1w);
    const size_t o = (size_t)(nb * 32 + n) * KP + kb * 32 + kq;
    uint2 hv; hv.x = h0; hv.y = h1w;
    uint2 lv; lv.x = l0; lv.y = l1w;
    *(uint2*)(WtH + o) = hv;
    *(uint2*)(WtL + o) = lv;
}

// ---------------- enc1: verbatim round-6 proven kernel (51 us) ----------------
__global__ __launch_bounds__(256, 3) void enc1_kernel(
    const float* __restrict__ x, const ushort* __restrict__ WtH,
    const ushort* __restrict__ WtL, const float* __restrict__ b1,
    float* __restrict__ h1)
{
    __shared__ alignas(16) unsigned char AhiS[16384];
    __shared__ alignas(16) unsigned char AloS[16384];
    __shared__ alignas(16) unsigned char BhiS[8192];
    __shared__ alignas(16) unsigned char BloS[8192];

    const int tid = threadIdx.x;
    const int bx  = blockIdx.x;
    const int wk  = (bx & 7) * 64 + (bx >> 3);       // XCD-contiguous (512 = 8*64, bijective)
    const int n0  = (wk & 3) * 64;
    const int m0  = (wk >> 2) * 128;

    const int m_s = tid >> 1, kh = tid & 1;          // A: row, 32-k half
    const int n_s = tid >> 2, kq = tid & 3;          // B: row, 16-k quarter
    const float*  xrow = x + (size_t)(m0 + m_s) * D_IN;
    const ushort* bhrow = WtH + (size_t)(n0 + n_s) * KP + kq * 16;
    const ushort* blrow = WtL + (size_t)(n0 + n_s) * KP + kq * 16;
    const unsigned offB0 = (unsigned)(n_s * 128) + (unsigned)(((2 * kq)     ^ (n_s & 7)) << 4);
    const unsigned offB1 = (unsigned)(n_s * 128) + (unsigned)(((2 * kq + 1) ^ (n_s & 7)) << 4);

    const int lane = tid & 63;
    const int wid  = tid >> 6;
    const int wm   = wid >> 1, wn = wid & 1;
    const int fr   = lane & 15, g = lane >> 4;
    const unsigned swz = (unsigned)((fr & 7) << 4);
    const int kgb  = g * 16;

    f32x4v acc[4][2];
    #pragma unroll
    for (int mi = 0; mi < 4; ++mi)
        #pragma unroll
        for (int ni = 0; ni < 2; ++ni) acc[mi][ni] = (f32x4v){0.f, 0.f, 0.f, 0.f};

    for (int kt = 0; kt < 13; ++kt) {
        const int kbase = kt * 64 + kh * 32;
        float4 av[8];
        #pragma unroll
        for (int q = 0; q < 8; ++q) {
            const int kk = kbase + q * 4;
            float4 z4 = {0.f, 0.f, 0.f, 0.f};
            av[q] = (kk < D_IN) ? *(const float4*)(xrow + kk) : z4;
        }
        #pragma unroll
        for (int q16 = 0; q16 < 4; ++q16) {
            uint4 hw, lw;
            split_pair(av[2 * q16].x,     av[2 * q16].y,     hw.x, lw.x);
            split_pair(av[2 * q16].z,     av[2 * q16].w,     hw.y, lw.y);
            split_pair(av[2 * q16 + 1].x, av[2 * q16 + 1].y, hw.z, lw.z);
            split_pair(av[2 * q16 + 1].z, av[2 * q16 + 1].w, hw.w, lw.w);
            const unsigned off = (unsigned)(m_s * 128) +
                (unsigned)((((kh * 4 + q16) ^ (m_s & 7))) << 4);
            *(uint4*)(AhiS + off) = hw;
            *(uint4*)(AloS + off) = lw;
        }
        {
            const int ko = kt * 64;
            uint4 h0 = *(const uint4*)(bhrow + ko);
            uint4 h1v = *(const uint4*)(bhrow + ko + 8);
            uint4 l0 = *(const uint4*)(blrow + ko);
            uint4 l1v = *(const uint4*)(blrow + ko + 8);
            *(uint4*)(BhiS + offB0) = h0;
            *(uint4*)(BhiS + offB1) = h1v;
            *(uint4*)(BloS + offB0) = l0;
            *(uint4*)(BloS + offB1) = l1v;
        }
        __syncthreads();

        #pragma unroll
        for (int ks = 0; ks < 2; ++ks) {
            const unsigned kb = (unsigned)(ks * 64 + kgb);
            bf16x8 ahv[4], alv[4];
            #pragma unroll
            for (int mi = 0; mi < 4; ++mi) {
                const unsigned off = (unsigned)((wm * 64 + mi * 16 + fr) * 128) + (kb ^ swz);
                ahv[mi] = *(const bf16x8*)(AhiS + off);
                alv[mi] = *(const bf16x8*)(AloS + off);
            }
            #pragma unroll
            for (int ni = 0; ni < 2; ++ni) {
                const unsigned offb = (unsigned)((wn * 32 + ni * 16 + fr) * 128) + (kb ^ swz);
                bf16x8 bh = *(const bf16x8*)(BhiS + offb);
                bf16x8 bl = *(const bf16x8*)(BloS + offb);
                #pragma unroll
                for (int mi = 0; mi < 4; ++mi) {
                    acc[mi][ni] = __builtin_amdgcn_mfma_f32_16x16x32_bf16(ahv[mi], bh, acc[mi][ni], 0, 0, 0);
                    acc[mi][ni] = __builtin_amdgcn_mfma_f32_16x16x32_bf16(ahv[mi], bl, acc[mi][ni], 0, 0, 0);
                    acc[mi][ni] = __builtin_amdgcn_mfma_f32_16x16x32_bf16(alv[mi], bh, acc[mi][ni], 0, 0, 0);
                }
            }
        }
        __syncthreads();
    }

    #pragma unroll
    for (int ni = 0; ni < 2; ++ni) {
        const int col = n0 + wn * 32 + ni * 16 + fr;
        const float bias = b1[col];
        #pragma unroll
        for (int mi = 0; mi < 4; ++mi) {
            #pragma unroll
            for (int r = 0; r < 4; ++r) {
                const int row = m0 + wm * 64 + mi * 16 + g * 4 + r;
                h1[(size_t)row * 256 + col] = tanhf(acc[mi][ni][r] + bias);
            }
        }
    }
}

// ---------------- stepA2F: enc2 fused into stepA2 t=0 ----------------
// Phase 1 = enc2 (identical thread map: r=tid>>3 == grp, d=tid&7 == sub);
// Phase 2 = stepA2 t=0 body. hs buffer reused for act/red2 after phase 1.
__global__ __launch_bounds__(256) void stepA2f_kernel(
    const float* __restrict__ h1, const float* __restrict__ W2,
    const float* __restrict__ b2,
    float* __restrict__ zT, float* __restrict__ hT,
    const float* __restrict__ mu, const float* __restrict__ c,
    const float* __restrict__ Wp, const float* __restrict__ bp,
    float* __restrict__ part)
{
    __shared__ alignas(16) float pool[8320];   // phase1: hs[32][260]; phase2: act[32*72] + red2 @2304
    __shared__ alignas(16) float w2t[8][260];
    __shared__ alignas(16) float mu_s[64];
    __shared__ alignas(16) float bp_s[64];
    __shared__ alignas(16) float c_s[512];
    __shared__ alignas(16) float wp_s[512];
    __shared__ alignas(16) float z_s[256];
    __shared__ alignas(16) float post_s[32];
    const int tid = threadIdx.x;
    const int r0 = blockIdx.x * 32;

    for (int i = tid; i < D_HID * D_LAT; i += 256) {
        int k = i >> 3, d = i & 7;
        w2t[d][k] = W2[i];
    }
    if (tid < 64) { mu_s[tid] = mu[tid]; bp_s[tid] = bp[tid]; }
    for (int i = tid; i < 512; i += 256) { c_s[i] = c[i]; wp_s[i] = Wp[i]; }
    #pragma unroll
    for (int i = 0; i < 8; ++i) {
        int idx = tid + i * 256;
        int rr = idx >> 6, c4 = idx & 63;
        float4 v = *(const float4*)(h1 + (size_t)(r0 + rr) * D_HID + c4 * 4);
        *(float4*)&pool[rr * 260 + c4 * 4] = v;
    }
    __syncthreads();

    // ---- phase 1: zown = h1[row] @ W2[:,sub] + b2[sub] (identical to enc2) ----
    const int sub = tid & 7;
    const int grp = tid >> 3;
    const int b   = r0 + grp;
    float accz = 0.f;
    #pragma unroll 8
    for (int k4 = 0; k4 < 64; ++k4) {
        float4 a = *(const float4*)&pool[grp * 260 + k4 * 4];
        float4 w = *(const float4*)&w2t[sub][k4 * 4];
        accz = fmaf(a.x, w.x, accz);
        accz = fmaf(a.y, w.y, accz);
        accz = fmaf(a.z, w.z, accz);
        accz = fmaf(a.w, w.w, accz);
    }
    const float zown = accz + b2[sub];
    __syncthreads();   // hs dead -> pool reusable

    // ---- phase 2: stepA2 t=0 body ----
    const int lane = tid & 63;
    const int gbase = lane & ~7;
    float z[8];
    #pragma unroll
    for (int d = 0; d < 8; ++d) z[d] = __shfl(zown, gbase + d, 64);

    #pragma unroll 1
    for (int it = 0; it < PM_STEPS; ++it) {
        float f[8];
        #pragma unroll
        for (int d = 0; d < 8; ++d) f[d] = 0.f;
        #pragma unroll
        for (int k = 0; k < 8; ++k) {
            const int n = sub + 8 * k;
            float dx[8];
            float r2 = EPS_C;
            #pragma unroll
            for (int d = 0; d < 8; ++d) {
                dx[d] = c_s[n * 8 + d] - z[d];
                r2 = fmaf(dx[d], dx[d], r2);
            }
            float wgt = mu_s[n] * fast_rcp(r2);
            #pragma unroll
            for (int d = 0; d < 8; ++d) f[d] = fmaf(wgt, dx[d], f[d]);
        }
        #pragma unroll
        for (int d = 0; d < 8; ++d) f[d] = DPP_XOR_ADD(f[d], 0xB1);
        #pragma unroll
        for (int d = 0; d < 8; ++d) f[d] = DPP_XOR_ADD(f[d], 0x4E);
        #pragma unroll
        for (int d = 0; d < 8; ++d) f[d] += __shfl_xor(f[d], 4, 64);
        #pragma unroll
        for (int d = 0; d < 8; ++d) z[d] = fmaf(DT_C, f[d], z[d]);
    }
    float zsel = z[0];
    #pragma unroll
    for (int d = 1; d < 8; ++d) if (sub == d) zsel = z[d];
    zT[(size_t)b * 8 + sub] = zsel;

    float hn[8];
    float s = 0.f;
    #pragma unroll
    for (int j = 0; j < 8; ++j) {
        const int ch = sub * 8 + j;
        float a = bp_s[ch];
        #pragma unroll
        for (int d = 0; d < 8; ++d) a = fmaf(z[d], wp_s[d * 64 + ch], a);
        hn[j] = MGAIN * fast_tanh(a);
        s += hn[j];
    }
    s = DPP_XOR_ADD(s, 0xB1);
    s = DPP_XOR_ADD(s, 0x4E);
    s += __shfl_xor(s, 4, 64);
    const float mean = s * (1.f / 64.f);
    float spost = 0.f;
    #pragma unroll
    for (int j = 0; j < 8; ++j) {
        hn[j] = hn[j] + EIG * (hn[j] - mean);
        spost += hn[j];
    }
    {
        float4 a0 = {hn[0], hn[1], hn[2], hn[3]};
        float4 a1 = {hn[4], hn[5], hn[6], hn[7]};
        float4* hp = (float4*)(hT + (size_t)b * 64 + sub * 8);
        hp[0] = a0; hp[1] = a1;
    }
    spost = DPP_XOR_ADD(spost, 0xB1);
    spost = DPP_XOR_ADD(spost, 0x4E);
    spost += __shfl_xor(spost, 4, 64);

    z_s[tid] = zsel;
    if (sub == 0) post_s[grp] = spost * (1.f / 64.f);
    #pragma unroll
    for (int k = 0; k < 8; ++k) {
        const int n = sub + 8 * k;
        float r2 = 0.f;
        #pragma unroll
        for (int d = 0; d < 8; ++d) {
            float dd = c_s[n * 8 + d] - z[d];
            r2 = fmaf(dd, dd, r2);
        }
        pool[grp * 72 + n] = __expf(-r2);
    }
    __syncthreads();
    {
        float* red2 = pool + 2304;
        const int q = tid >> 6, n2 = tid & 63;
        float r[10];
        #pragma unroll
        for (int j = 0; j < 10; ++j) r[j] = 0.f;
        #pragma unroll
        for (int i = 0; i < 8; ++i) {
            const int g2 = q * 8 + i;
            float a = pool[g2 * 72 + n2];
            const float4* zp = (const float4*)&z_s[g2 * 8];
            float4 za = zp[0], zb = zp[1];
            r[0] += a;
            r[1] = fmaf(a, post_s[g2], r[1]);
            r[2] = fmaf(a, za.x, r[2]);
            r[3] = fmaf(a, za.y, r[3]);
            r[4] = fmaf(a, za.z, r[4]);
            r[5] = fmaf(a, za.w, r[5]);
            r[6] = fmaf(a, zb.x, r[6]);
            r[7] = fmaf(a, zb.y, r[7]);
            r[8] = fmaf(a, zb.z, r[8]);
            r[9] = fmaf(a, zb.w, r[9]);
        }
        #pragma unroll
        for (int j = 0; j < 10; ++j) red2[(q * 64 + n2) * 10 + j] = r[j];
        __syncthreads();
        if (q == 0) {
            #pragma unroll
            for (int j = 0; j < 10; ++j) {
                float sv = (red2[(n2) * 10 + j] + red2[(64 + n2) * 10 + j]) +
                           (red2[(128 + n2) * 10 + j] + red2[(192 + n2) * 10 + j]);
                part[((size_t)blockIdx.x * 64 + n2) * 10 + j] = sv;
            }
        }
    }
}

// ---------------- stepA2: verbatim round-6 proven kernel (t >= 1) ----------------
__global__ __launch_bounds__(256) void stepA2_kernel(
    float* __restrict__ zT, float* __restrict__ hT,
    const float* __restrict__ mu, const float* __restrict__ c,
    const float* __restrict__ Wp, const float* __restrict__ bp,
    const float* __restrict__ Wr, const float* __restrict__ br,
    float* __restrict__ part, float* __restrict__ out, int t)
{
    __shared__ alignas(16) float mu_s[64];
    __shared__ alignas(16) float c_s[512];
    __shared__ alignas(16) float wp_s[512];
    __shared__ alignas(16) float bp_s[64];
    __shared__ alignas(16) float wr_s[704];
    __shared__ alignas(16) float br_s[16];
    __shared__ alignas(16) float act_s[32 * 72];
    __shared__ alignas(16) float z_s[256];
    __shared__ alignas(16) float post_s[32];
    __shared__ alignas(16) float red2[4 * 64 * 10];
    const int tid = threadIdx.x;
    if (tid < 64) { mu_s[tid] = mu[tid]; bp_s[tid] = bp[tid]; }
    for (int i = tid; i < 512; i += 256) { c_s[i] = c[i]; wp_s[i] = Wp[i]; }
    const bool last = (t == T_STEPS - 1);
    if (last) {
        for (int i = tid; i < 640; i += 256) wr_s[(i / 10) * 11 + (i % 10)] = Wr[i];
        if (tid < N_CLS) br_s[tid] = br[tid];
    }
    __syncthreads();

    const int sub  = tid & 7;
    const int grp  = tid >> 3;
    const int b    = blockIdx.x * 32 + grp;
    const int lane = tid & 63;
    const int gbase = lane & ~7;

    float zown = zT[(size_t)b * 8 + sub];
    float z[8];
    #pragma unroll
    for (int d = 0; d < 8; ++d) z[d] = __shfl(zown, gbase + d, 64);

    #pragma unroll 1
    for (int it = 0; it < PM_STEPS; ++it) {
        float f[8];
        #pragma unroll
        for (int d = 0; d < 8; ++d) f[d] = 0.f;
        #pragma unroll
        for (int k = 0; k < 8; ++k) {
            const int n = sub + 8 * k;
            float dx[8];
            float r2 = EPS_C;
            #pragma unroll
            for (int d = 0; d < 8; ++d) {
                dx[d] = c_s[n * 8 + d] - z[d];
                r2 = fmaf(dx[d], dx[d], r2);
            }
            float wgt = mu_s[n] * fast_rcp(r2);
            #pragma unroll
            for (int d = 0; d < 8; ++d) f[d] = fmaf(wgt, dx[d], f[d]);
        }
        #pragma unroll
        for (int d = 0; d < 8; ++d) f[d] = DPP_XOR_ADD(f[d], 0xB1);
        #pragma unroll
        for (int d = 0; d < 8; ++d) f[d] = DPP_XOR_ADD(f[d], 0x4E);
        #pragma unroll
        for (int d = 0; d < 8; ++d) f[d] += __shfl_xor(f[d], 4, 64);
        #pragma unroll
        for (int d = 0; d < 8; ++d) z[d] = fmaf(DT_C, f[d], z[d]);
    }
    float zsel = z[0];
    #pragma unroll
    for (int d = 1; d < 8; ++d) if (sub == d) zsel = z[d];
    zT[(size_t)b * 8 + sub] = zsel;

    float hn[8];
    float s = 0.f;
    #pragma unroll
    for (int j = 0; j < 8; ++j) {
        const int ch = sub * 8 + j;
        float a = bp_s[ch];
        #pragma unroll
        for (int d = 0; d < 8; ++d) a = fmaf(z[d], wp_s[d * 64 + ch], a);
        hn[j] = fast_tanh(a);
    }
    {
        const float4* hp = (const float4*)(hT + (size_t)b * 64 + sub * 8);
        float4 h0 = hp[0], h1v = hp[1];
        hn[0] = TAU_C * h0.x + MGAIN * hn[0];
        hn[1] = TAU_C * h0.y + MGAIN * hn[1];
        hn[2] = TAU_C * h0.z + MGAIN * hn[2];
        hn[3] = TAU_C * h0.w + MGAIN * hn[3];
        hn[4] = TAU_C * h1v.x + MGAIN * hn[4];
        hn[5] = TAU_C * h1v.y + MGAIN * hn[5];
        hn[6] = TAU_C * h1v.z + MGAIN * hn[6];
        hn[7] = TAU_C * h1v.w + MGAIN * hn[7];
        #pragma unroll
        for (int j = 0; j < 8; ++j) s += hn[j];
    }
    s = DPP_XOR_ADD(s, 0xB1);
    s = DPP_XOR_ADD(s, 0x4E);
    s += __shfl_xor(s, 4, 64);
    const float mean = s * (1.f / 64.f);
    float spost = 0.f;
    #pragma unroll
    for (int j = 0; j < 8; ++j) {
        hn[j] = hn[j] + EIG * (hn[j] - mean);
        spost += hn[j];
    }
    {
        float4 a0 = {hn[0], hn[1], hn[2], hn[3]};
        float4 a1 = {hn[4], hn[5], hn[6], hn[7]};
        float4* hp = (float4*)(hT + (size_t)b * 64 + sub * 8);
        hp[0] = a0; hp[1] = a1;
    }
    spost = DPP_XOR_ADD(spost, 0xB1);
    spost = DPP_XOR_ADD(spost, 0x4E);
    spost += __shfl_xor(spost, 4, 64);

    if (!last) {
        z_s[tid] = zsel;
        if (sub == 0) post_s[grp] = spost * (1.f / 64.f);
        #pragma unroll
        for (int k = 0; k < 8; ++k) {
            const int n = sub + 8 * k;
            float r2 = 0.f;
            #pragma unroll
            for (int d = 0; d < 8; ++d) {
                float dd = c_s[n * 8 + d] - z[d];
                r2 = fmaf(dd, dd, r2);
            }
            act_s[grp * 72 + n] = __expf(-r2);
        }
        __syncthreads();
        const int q = tid >> 6, n2 = tid & 63;
        float r[10];
        #pragma unroll
        for (int j = 0; j < 10; ++j) r[j] = 0.f;
        #pragma unroll
        for (int i = 0; i < 8; ++i) {
            const int g2 = q * 8 + i;
            float a = act_s[g2 * 72 + n2];
            const float4* zp = (const float4*)&z_s[g2 * 8];
            float4 za = zp[0], zb = zp[1];
            r[0] += a;
            r[1] = fmaf(a, post_s[g2], r[1]);
            r[2] = fmaf(a, za.x, r[2]);
            r[3] = fmaf(a, za.y, r[3]);
            r[4] = fmaf(a, za.z, r[4]);
            r[5] = fmaf(a, za.w, r[5]);
            r[6] = fmaf(a, zb.x, r[6]);
            r[7] = fmaf(a, zb.y, r[7]);
            r[8] = fmaf(a, zb.z, r[8]);
            r[9] = fmaf(a, zb.w, r[9]);
        }
        #pragma unroll
        for (int j = 0; j < 10; ++j) red2[(q * 64 + n2) * 10 + j] = r[j];
        __syncthreads();
        if (q == 0) {
            #pragma unroll
            for (int j = 0; j < 10; ++j) {
                float sv = (red2[(n2) * 10 + j] + red2[(64 + n2) * 10 + j]) +
                           (red2[(128 + n2) * 10 + j] + red2[(192 + n2) * 10 + j]);
                part[((size_t)blockIdx.x * 64 + n2) * 10 + j] = sv;
            }
        }
    } else {
        float lg[N_CLS];
        #pragma unroll
        for (int cls = 0; cls < N_CLS; ++cls) lg[cls] = 0.f;
        #pragma unroll
        for (int j = 0; j < 8; ++j) {
            const int ch = sub * 8 + j;
            #pragma unroll
            for (int cls = 0; cls < N_CLS; ++cls)
                lg[cls] = fmaf(hn[j], wr_s[ch * 11 + cls], lg[cls]);
        }
        #pragma unroll
        for (int cls = 0; cls < N_CLS; ++cls) {
            lg[cls] = DPP_XOR_ADD(lg[cls], 0xB1);
            lg[cls] = DPP_XOR_ADD(lg[cls], 0x4E);
            lg[cls] += __shfl_xor(lg[cls], 4, 64);
        }
        if (sub == 0) {
            #pragma unroll
            for (int cls = 0; cls < N_CLS; ++cls)
                out[(size_t)b * 10 + cls] = lg[cls] + br_s[cls];
        }
        out[163840 + (size_t)b * 8 + sub] = zsel;
        {
            float4 a0 = {hn[0], hn[1], hn[2], hn[3]};
            float4 a1 = {hn[4], hn[5], hn[6], hn[7]};
            float4* op = (float4*)(out + 294912 + (size_t)b * 64 + sub * 8);
            op[0] = a0; op[1] = a1;
        }
    }
}

// ---------------- stepB2: reduce 512 partials -> mu', c' ----------------
__global__ __launch_bounds__(256) void stepB2_kernel(
    const float* __restrict__ part,
    const float* __restrict__ mu_in, const float* __restrict__ c_in,
    float* __restrict__ mu_out, float* __restrict__ c_out)
{
    const int n = blockIdx.x, tid = threadIdx.x;
    __shared__ float red[256][10];
    const float* p0 = part + ((size_t)tid * 64 + n) * 10;
    const float* p1 = part + ((size_t)(tid + 256) * 64 + n) * 10;
    #pragma unroll
    for (int j = 0; j < 10; ++j) red[tid][j] = p0[j] + p1[j];
    __syncthreads();
    for (int s = 128; s > 0; s >>= 1) {
        if (tid < s) {
            #pragma unroll
            for (int j = 0; j < 10; ++j) red[tid][j] += red[tid + s][j];
        }
        __syncthreads();
    }
    if (tid == 0) {
        const float S1 = red[0][0];
        const float S2 = red[0][1] * (1.f / B_N);
        mu_out[n] = mu_in[n] + PLR_C * S2;
        const float denom = S1 + EPS_C;
        #pragma unroll
        for (int d = 0; d < 8; ++d) {
            float s3 = red[0][2 + d];
            c_out[n * 8 + d] = c_in[n * 8 + d] + PLR_C * (s3 / denom - c_in[n * 8 + d] * (S1 / denom));
        }
    }
}

extern "C" void kernel_launch(void* const* d_in, const int* in_sizes, int n_in,
                              void* d_out, int out_size, void* d_ws, size_t ws_size,
                              hipStream_t stream) {
    (void)in_sizes; (void)n_in; (void)out_size; (void)ws_size;
    const float* x   = (const float*)d_in[0];
    const float* W1  = (const float*)d_in[1];
    const float* b1  = (const float*)d_in[2];
    const float* W2  = (const float*)d_in[3];
    const float* b2  = (const float*)d_in[4];
    const float* mu0 = (const float*)d_in[5];
    const float* c0  = (const float*)d_in[6];
    const float* Wp  = (const float*)d_in[7];
    const float* bp  = (const float*)d_in[8];
    const float* Wr  = (const float*)d_in[9];
    const float* br  = (const float*)d_in[10];
    float* out = (float*)d_out;
    float* ws  = (float*)d_ws;

    // ws layout (floats), NO aliasing (ws >= 34.9 MB verified in round 9):
    float* h1    = ws;                       // [B,256]       4,194,304
    float* part  = ws + 4194304;             // [512][64][10]   327,680
    float* zT    = ws + 4521984;             // [B][8]          131,072
    float* mu_buf = ws + 4653056;            // 2 x 64
    float* c_buf  = ws + 4653184;            // 2 x 512
    ushort* WtH  = (ushort*)(ws + 4654208);  // [256][832] bf16
    ushort* WtL  = (ushort*)(ws + 4760704);  // [256][832] bf16
    float* hT    = ws + 4867200;             // [B][64]       1,048,576

    w1t_kernel<<<dim3(26, 8), 256, 0, stream>>>(W1, WtH, WtL);
    enc1_kernel<<<512, 256, 0, stream>>>(x, WtH, WtL, b1, h1);

    // t = 0: fused enc2 + stepA2
    stepA2f_kernel<<<512, 256, 0, stream>>>(h1, W2, b2, zT, hT, mu0, c0, Wp, bp, part);
    stepB2_kernel<<<64, 256, 0, stream>>>(part, mu0, c0, mu_buf, c_buf);

    const float* mu_cur = mu_buf;
    const float* c_cur  = c_buf;
    for (int t = 1; t < T_STEPS; ++t) {
        stepA2_kernel<<<512, 256, 0, stream>>>(zT, hT, mu_cur, c_cur, Wp, bp, Wr, br,
                                               part, out, t);
        if (t < T_STEPS - 1) {
            float* mo = mu_buf + (t & 1) * 64;
            float* co = c_buf  + (t & 1) * 512;
            stepB2_kernel<<<64, 256, 0, stream>>>(part, mu_cur, c_cur, mo, co);
            mu_cur = mo;
            c_cur  = co;
        }
    }
}